// Round 3
// baseline (241.646 us; speedup 1.0000x reference)
//
#include <hip/hip_runtime.h>
#include <hip/hip_bf16.h>
#include <stdint.h>

typedef unsigned short u16;
typedef short bf16x8 __attribute__((ext_vector_type(8)));
typedef float f32x4 __attribute__((ext_vector_type(4)));

#define DEVI static __device__ __forceinline__

#if __has_builtin(__builtin_amdgcn_exp2f)
#define EXP2F(x) __builtin_amdgcn_exp2f(x)
#else
#define EXP2F(x) exp2f(x)
#endif

DEVI u16 f2bf(float f) {
  union { float f; uint32_t u; } v; v.f = f;
  uint32_t u = v.u;
  u += 0x7fffu + ((u >> 16) & 1u);   // round-to-nearest-even
  return (u16)(u >> 16);
}
DEVI uint32_t pk2bf(float lo, float hi) {
  __hip_bfloat162 h = __float22bfloat162_rn(float2{lo, hi});
  union { __hip_bfloat162 h; uint32_t u; } v; v.h = h; return v.u;
}

DEVI void async16(const void* g, const void* l) {
  __builtin_amdgcn_global_load_lds(
      (const __attribute__((address_space(1))) void*)g,
      (__attribute__((address_space(3))) void*)l, 16, 0, 0);
}

DEVI f32x4 mfma16(bf16x8 a, bf16x8 b, f32x4 c) {
  return __builtin_amdgcn_mfma_f32_16x16x32_bf16(a, b, c, 0, 0, 0);
}

// ---------------------------------------------------------------- constants
// B=2, S=2048, H=1024, NH=16, D=64, M=B*S=4096
// log2(e)/sqrt(64): folded into Q at the qkv epilogue
#define CSC 0.18033688011112042f

// P-tile LDS row stride (u16). 76 -> P b128 read is ~4-way banked (72 was 8-way).
#define PSTR 76

// ------------------------------------------------- kernel 1: fp32 -> bf16 x
__global__ void convx(const float* __restrict__ q, const float* __restrict__ k,
                      const float* __restrict__ v, u16* __restrict__ out) {
  const int z = blockIdx.y;
  const float* src = (z == 0) ? q : (z == 1) ? k : v;
  const int i = (blockIdx.x * 256 + threadIdx.x) * 4;
  float4 f = *(const float4*)(src + i);
  ushort4 o;
  o.x = f2bf(f.x); o.y = f2bf(f.y); o.z = f2bf(f.z); o.w = f2bf(f.w);
  *(ushort4*)(out + (size_t)z * 4194304 + i) = o;
}

// ----------------------------------- kernel 2: W[k][n] -> Wt[n][k] in bf16
__global__ void transw(const float* __restrict__ Wq, const float* __restrict__ Wk,
                       const float* __restrict__ Wv, const float* __restrict__ Wo,
                       u16* __restrict__ WT) {
  __shared__ u16 tile[64 * 68];
  const int z = blockIdx.z;
  const float* W = (z == 0) ? Wq : (z == 1) ? Wk : (z == 2) ? Wv : Wo;
  u16* out = WT + (size_t)z * 1048576;
  const int R0 = blockIdx.y * 64, C0 = blockIdx.x * 64;
  const int t = threadIdx.x;
#pragma unroll
  for (int it = 0; it < 16; ++it) {
    int j = it * 256 + t;
    int r = j >> 6, c = j & 63;
    tile[r * 68 + c] = f2bf(W[(size_t)(R0 + r) * 1024 + C0 + c]);
  }
  __syncthreads();
#pragma unroll
  for (int it = 0; it < 16; ++it) {
    int j = it * 256 + t;
    int c = j >> 6, r = j & 63;
    out[(size_t)(C0 + c) * 1024 + R0 + r] = tile[r * 68 + c];
  }
}

// -------------------------------------------------- fused QKV projection GEMM
// BK=64, 16 k-iters, uniform C^T orientation (regs = n = d-dim) for ALL z.
// Epilogue bounces acc through LDS so every global store is a 256B-contiguous
// run (full-line coverage). z=0: Q natural [b,s,1024] pre-scaled by CSC;
// z=1: K natural [b,s,1024]; z=2: V^T [b,h,d,s].
// XCD swizzle: 1-D grid of 256 tiles, m_tile = T&31 -> same-A-stripe blocks
// share an XCD (xcd = T%8 = m%8); per-XCD: 4 A-stripes + full B = 3MB < 4MB L2.
__global__ __launch_bounds__(256, 3)
void qkv_gemm(const u16* __restrict__ XB, const u16* __restrict__ WT,
              const float* __restrict__ bq, const float* __restrict__ bk,
              const float* __restrict__ bv,
              u16* __restrict__ QN, u16* __restrict__ KN, u16* __restrict__ VT) {
  __shared__ u16 smem[16896];          // lA(8192) + lB(8192); reused as 128x132 bounce
  u16* lA = smem;
  u16* lB = smem + 8192;
  const int z = blockIdx.y;
  const u16* A  = XB + (size_t)z * 4194304;
  const u16* Bt = WT + (size_t)z * 1048576;
  const float* bias = (z == 0) ? bq : (z == 1) ? bk : bv;
  const int T = blockIdx.x;
  const int m0 = (T & 31) * 128, n0 = (T >> 5) * 128;
  const int t = threadIdx.x, lane = t & 63, w = t >> 6;
  const int quad = lane >> 4, l16 = lane & 15;
  const int wm = (w & 1) * 64, wn = (w >> 1) * 64;

  f32x4 acc[4][4] = {};
  for (int kt = 0; kt < 16; ++kt) {
    const int k0 = kt * 64;
#pragma unroll
    for (int it = 0; it < 4; ++it) {
      int i = it * 256 + t;
      int r = i >> 3, cc = i & 7, c = cc ^ (r & 7);
      async16(A + (size_t)(m0 + r) * 1024 + k0 + c * 8, &lA[i * 8]);
      async16(Bt + (size_t)(n0 + r) * 1024 + k0 + c * 8, &lB[i * 8]);
    }
    __syncthreads();
#pragma unroll
    for (int ks = 0; ks < 2; ++ks) {
      bf16x8 af[4], bfr[4];
#pragma unroll
      for (int rt = 0; rt < 4; ++rt) {
        int row = wm + rt * 16 + l16;
        af[rt] = *(const bf16x8*)&lA[row * 64 + ((ks * 4 + quad) ^ (row & 7)) * 8];
      }
#pragma unroll
      for (int ct = 0; ct < 4; ++ct) {
        int row = wn + ct * 16 + l16;
        bfr[ct] = *(const bf16x8*)&lB[row * 64 + ((ks * 4 + quad) ^ (row & 7)) * 8];
      }
#pragma unroll
      for (int rt = 0; rt < 4; ++rt)
#pragma unroll
        for (int ct = 0; ct < 4; ++ct)
          acc[rt][ct] = mfma16(bfr[ct], af[rt], acc[rt][ct]);  // C^T: regs = d
    }
    __syncthreads();
  }

  // ---- epilogue via LDS bounce (all waves past final barrier; smem reusable)
  if (z < 2) {
    const float scl = (z == 0) ? CSC : 1.0f;
    // acc -> smem[s][132 + d]  (s-local = wm+rt*16+l16, d-local = wn+ct*16+quad*4)
#pragma unroll
    for (int rt = 0; rt < 4; ++rt) {
      int sl = wm + rt * 16 + l16;
#pragma unroll
      for (int ct = 0; ct < 4; ++ct) {
        int nb = wn + ct * 16 + quad * 4;
        float4 b4 = *(const float4*)&bias[n0 + nb];
        ushort4 pk;
        pk.x = f2bf((acc[rt][ct][0] + b4.x) * scl);
        pk.y = f2bf((acc[rt][ct][1] + b4.y) * scl);
        pk.z = f2bf((acc[rt][ct][2] + b4.z) * scl);
        pk.w = f2bf((acc[rt][ct][3] + b4.w) * scl);
        *(ushort4*)&smem[sl * 132 + nb] = pk;
      }
    }
    __syncthreads();
    // coalesced store: natural [4096][1024]; 256B-contiguous per 16 lanes
    u16* out = (z == 0) ? QN : KN;
#pragma unroll
    for (int p = 0; p < 8; ++p) {
      int idx = p * 256 + t;
      int row = idx >> 4, chunk = idx & 15;
      *(bf16x8*)&out[(size_t)(m0 + row) * 1024 + n0 + chunk * 8] =
          *(const bf16x8*)&smem[row * 132 + chunk * 8];
    }
  } else {
    // acc -> smem[d][132 + s] (transpose via scalar LDS writes)
#pragma unroll
    for (int rt = 0; rt < 4; ++rt) {
      int sl = wm + rt * 16 + l16;
#pragma unroll
      for (int ct = 0; ct < 4; ++ct) {
        int nb = wn + ct * 16 + quad * 4;
        float4 b4 = *(const float4*)&bias[n0 + nb];
        smem[(nb + 0) * 132 + sl] = f2bf(acc[rt][ct][0] + b4.x);
        smem[(nb + 1) * 132 + sl] = f2bf(acc[rt][ct][1] + b4.y);
        smem[(nb + 2) * 132 + sl] = f2bf(acc[rt][ct][2] + b4.z);
        smem[(nb + 3) * 132 + sl] = f2bf(acc[rt][ct][3] + b4.w);
      }
    }
    __syncthreads();
    // coalesced store: VT[b,h,d,s]; 256B-contiguous per 16 lanes
    const int bb = m0 >> 11, sb = m0 & 2047;
#pragma unroll
    for (int p = 0; p < 8; ++p) {
      int idx = p * 256 + t;
      int dl = idx >> 4, chunk = idx & 15;
      int ncol = n0 + dl, hh = ncol >> 6, dd = ncol & 63;
      *(bf16x8*)&VT[((size_t)((bb * 16 + hh) * 64 + dd)) * 2048 + sb + chunk * 8] =
          *(const bf16x8*)&smem[dl * 132 + chunk * 8];
    }
  }
}

// -------------------------------------------------------- flash attention
// attn7: post-mortem of attn5 (58.4us, 2 blk/CU) vs attn6 (62.2us, 1 blk/CU,
// half the LDS traffic) shows the kernel is latency/barrier-bound, NOT
// LDS-BW-bound: the per-tile vmcnt(0)+barrier drain needs other resident
// blocks to cover it. attn7 keeps the 2-q-set fragment reuse (2 MFMAs per
// K/V-frag ds_read, 2x compute per barrier) but at 4 waves/block (256 thr),
// 128 q/block, grid (16,16,2)=512 blocks -> 3 blocks/CU by LDS (51,968 B).
// lPT row stride 76 (was 72): P b128 read goes 8-way -> ~4-way banked.
// S^T formulation, no running max, Sk-tile=64, double-buffered K/V, one
// barrier/tile, setprio around MFMA clusters (T5).
__global__ __launch_bounds__(256, 3)
void attn7(const u16* __restrict__ QN, const u16* __restrict__ KN,
           const u16* __restrict__ VT, u16* __restrict__ AO) {
  __shared__ u16 lK[2][64 * 64];
  __shared__ u16 lV[2][64 * 64];
  __shared__ u16 lPT[4][32 * PSTR];
  const int qt0 = blockIdx.x, h = blockIdx.y, b = blockIdx.z;
  const int t = threadIdx.x, lane = t & 63, w = t >> 6;
  const int quad = lane >> 4, l16 = lane & 15;
  const u16* Qg = QN + ((size_t)(b * 2048 + qt0 * 128)) * 1024 + h * 64;
  const u16* Kg = KN + ((size_t)b * 2048) * 1024 + h * 64;
  const u16* Vg = VT + ((size_t)((b * 16 + h) * 64)) * 2048;

  // Q fragments straight from global (pre-scaled by CSC in qkv_gemm)
  // qf[qs][ks]: q rows w*32 + qs*16 + l16
  bf16x8 qf[2][2];
#pragma unroll
  for (int qs = 0; qs < 2; ++qs)
#pragma unroll
    for (int ks = 0; ks < 2; ++ks)
      qf[qs][ks] = *(const bf16x8*)(Qg + (size_t)(w * 32 + qs * 16 + l16) * 1024 +
                                    ks * 32 + quad * 8);

  // stage tile 0: K rows (natural, stride 1024), V rows (VT, stride 2048)
#pragma unroll
  for (int p = 0; p < 2; ++p) {
    int i = p * 256 + t;
    int r = i >> 3, cc = i & 7, c = cc ^ (r & 7);
    async16(Kg + (size_t)r * 1024 + c * 8, &lK[0][i * 8]);
    async16(Vg + (size_t)r * 2048 + c * 8, &lV[0][i * 8]);
  }
  __syncthreads();

  f32x4 o[2][4] = {};
  float lsum[2] = {0.f, 0.f};
  u16* myP = &lPT[w][0];

  for (int kt = 0; kt < 32; ++kt) {
    const int cur = kt & 1, nxt = cur ^ 1;
    if (kt + 1 < 32) {
      const int kb = (kt + 1) * 64;
#pragma unroll
      for (int p = 0; p < 2; ++p) {
        int i = p * 256 + t;
        int r = i >> 3, cc = i & 7, c = cc ^ (r & 7);
        async16(Kg + (size_t)(kb + r) * 1024 + c * 8, &lK[nxt][i * 8]);
        async16(Vg + (size_t)r * 2048 + kb + c * 8, &lV[nxt][i * 8]);
      }
    }

    // ---- QK^T -> S^T: rows sk (st*16+quad*4+r), cols q (l16); 2 q-sets
    f32x4 sc[2][4];
    __builtin_amdgcn_s_setprio(1);
#pragma unroll
    for (int st = 0; st < 4; ++st) {
      int row = st * 16 + l16;
      bf16x8 kf0 = *(const bf16x8*)&lK[cur][row * 64 + ((quad) ^ (row & 7)) * 8];
      bf16x8 kf1 = *(const bf16x8*)&lK[cur][row * 64 + ((4 + quad) ^ (row & 7)) * 8];
#pragma unroll
      for (int qs = 0; qs < 2; ++qs) {
        f32x4 z = {};
        sc[qs][st] = mfma16(kf0, qf[qs][0], z);
        sc[qs][st] = mfma16(kf1, qf[qs][1], sc[qs][st]);
      }
    }
    __builtin_amdgcn_s_setprio(0);

    // ---- p = exp2(s); pack RNE bf16 pairs; l += fp32 p
#pragma unroll
    for (int qs = 0; qs < 2; ++qs)
#pragma unroll
      for (int st = 0; st < 4; ++st) {
        float p0 = EXP2F(sc[qs][st][0]);
        float p1 = EXP2F(sc[qs][st][1]);
        float p2 = EXP2F(sc[qs][st][2]);
        float p3 = EXP2F(sc[qs][st][3]);
        lsum[qs] += (p0 + p1) + (p2 + p3);
        uint2 pk;
        pk.x = pk2bf(p0, p1);
        pk.y = pk2bf(p2, p3);
        *(uint2*)&myP[(qs * 16 + l16) * PSTR + st * 16 + quad * 4] = pk;
      }

    // ---- PV: O^T += V^T(64d x 64sk) * P(32q x 64sk); vf reused across q-sets
    __builtin_amdgcn_s_setprio(1);
#pragma unroll
    for (int ks2 = 0; ks2 < 2; ++ks2) {
      bf16x8 pf0 = *(const bf16x8*)&myP[(l16) * PSTR + ks2 * 32 + quad * 8];
      bf16x8 pf1 = *(const bf16x8*)&myP[(16 + l16) * PSTR + ks2 * 32 + quad * 8];
#pragma unroll
      for (int dt = 0; dt < 4; ++dt) {
        int row = dt * 16 + l16;
        bf16x8 vf = *(const bf16x8*)&lV[cur][row * 64 + ((ks2 * 4 + quad) ^ (row & 7)) * 8];
        o[0][dt] = mfma16(vf, pf0, o[0][dt]);
        o[1][dt] = mfma16(vf, pf1, o[1][dt]);
      }
    }
    __builtin_amdgcn_s_setprio(0);
    __syncthreads();
  }

  // ---- epilogue: O^T/l -> AO [b][s][h*64+d] bf16 (4 consecutive d per lane)
#pragma unroll
  for (int qs = 0; qs < 2; ++qs) {
    float l = lsum[qs];
    l += __shfl_xor(l, 16, 64);
    l += __shfl_xor(l, 32, 64);
    float inv = 1.0f / l;
    int qglob = qt0 * 128 + w * 32 + qs * 16 + l16;
    size_t base = ((size_t)(b * 2048 + qglob)) * 1024 + h * 64;
#pragma unroll
    for (int dt = 0; dt < 4; ++dt) {
      ushort4 pk;
      pk.x = f2bf(o[qs][dt][0] * inv);
      pk.y = f2bf(o[qs][dt][1] * inv);
      pk.z = f2bf(o[qs][dt][2] * inv);
      pk.w = f2bf(o[qs][dt][3] * inv);
      *(ushort4*)&AO[base + dt * 16 + quad * 4] = pk;
    }
  }
}

// ------------------------------------------------------- output projection
// 128m x 64n tiles, BK=64, 512 blocks, XCD swizzle (m_tile = T&31).
// Normal orientation; scalar f32 stores = 64B runs (R3-style, known-good).
__global__ __launch_bounds__(256, 2)
void oproj_gemm(const u16* __restrict__ AO, const u16* __restrict__ Bt,
                const float* __restrict__ bias, float* __restrict__ out) {
  __shared__ u16 lA[128 * 64];
  __shared__ u16 lB[64 * 64];
  const int T = blockIdx.x;
  const int m0 = (T & 31) * 128, n0 = (T >> 5) * 64;
  const int t = threadIdx.x, lane = t & 63, w = t >> 6;
  const int quad = lane >> 4, l16 = lane & 15;
  const int wm = (w & 1) * 64, wn = (w >> 1) * 32;

  f32x4 acc[4][2] = {};
  for (int kt = 0; kt < 16; ++kt) {
    const int k0 = kt * 64;
#pragma unroll
    for (int it = 0; it < 4; ++it) {
      int i = it * 256 + t;
      int r = i >> 3, cc = i & 7, c = cc ^ (r & 7);
      async16(AO + (size_t)(m0 + r) * 1024 + k0 + c * 8, &lA[i * 8]);
    }
#pragma unroll
    for (int it = 0; it < 2; ++it) {
      int i = it * 256 + t;
      int r = i >> 3, cc = i & 7, c = cc ^ (r & 7);
      async16(Bt + (size_t)(n0 + r) * 1024 + k0 + c * 8, &lB[i * 8]);
    }
    __syncthreads();
#pragma unroll
    for (int ks = 0; ks < 2; ++ks) {
      bf16x8 af[4], bfr[2];
#pragma unroll
      for (int rt = 0; rt < 4; ++rt) {
        int row = wm + rt * 16 + l16;
        af[rt] = *(const bf16x8*)&lA[row * 64 + ((ks * 4 + quad) ^ (row & 7)) * 8];
      }
#pragma unroll
      for (int ct = 0; ct < 2; ++ct) {
        int row = wn + ct * 16 + l16;
        bfr[ct] = *(const bf16x8*)&lB[row * 64 + ((ks * 4 + quad) ^ (row & 7)) * 8];
      }
#pragma unroll
      for (int rt = 0; rt < 4; ++rt)
#pragma unroll
        for (int ct = 0; ct < 2; ++ct)
          acc[rt][ct] = mfma16(af[rt], bfr[ct], acc[rt][ct]);
    }
    __syncthreads();
  }

#pragma unroll
  for (int ct = 0; ct < 2; ++ct) {
    int ncol = n0 + wn + ct * 16 + l16;
    float bvv = bias[ncol];
#pragma unroll
    for (int rt = 0; rt < 4; ++rt)
#pragma unroll
      for (int r = 0; r < 4; ++r) {
        int m = m0 + wm + rt * 16 + quad * 4 + r;
        out[(size_t)m * 1024 + ncol] = acc[rt][ct][r] + bvv;
      }
  }
}

// ------------------------------------------------------------------ launch
extern "C" void kernel_launch(void* const* d_in, const int* in_sizes, int n_in,
                              void* d_out, int out_size, void* d_ws, size_t ws_size,
                              hipStream_t stream) {
  const float* query = (const float*)d_in[0];
  const float* key   = (const float*)d_in[1];
  const float* value = (const float*)d_in[2];
  const float* Wq = (const float*)d_in[3];
  const float* bq = (const float*)d_in[4];
  const float* Wk = (const float*)d_in[5];
  const float* bk = (const float*)d_in[6];
  const float* Wv = (const float*)d_in[7];
  const float* bv = (const float*)d_in[8];
  const float* Wo = (const float*)d_in[9];
  const float* bo = (const float*)d_in[10];
  float* out = (float*)d_out;

  // workspace layout (u16 elements): total 28M u16 = 56 MB
  u16* WT = (u16*)d_ws;              // 4 x 1M  (Wq_t, Wk_t, Wv_t, Wo_t)
  u16* QN = WT + 4 * 1048576;        // 4M  natural [b,s,1024] (pre-scaled by CSC)
  u16* KN = QN + 4194304;            // 4M  natural [b,s,1024]
  u16* VT = KN + 4194304;            // 4M  [b,h,d,s]
  u16* XB = VT + 4194304;            // 3 x 4M bf16 copies of q,k,v
  u16* AO = XB;                      // attn out aliases XB (dead by then)

  convx<<<dim3(4096, 3), 256, 0, stream>>>(query, key, value, XB);
  transw<<<dim3(16, 16, 4), 256, 0, stream>>>(Wq, Wk, Wv, Wo, WT);
  qkv_gemm<<<dim3(256, 3), 256, 0, stream>>>(XB, WT, bq, bk, bv, QN, KN, VT);
  attn7<<<dim3(16, 16, 2), 256, 0, stream>>>(QN, KN, VT, AO);
  oproj_gemm<<<dim3(512), 256, 0, stream>>>(AO, WT + 3 * 1048576, bo, out);
}

// Round 4
// 215.366 us; speedup vs baseline: 1.1220x; 1.1220x over previous
//
#include <hip/hip_runtime.h>
#include <hip/hip_bf16.h>
#include <stdint.h>

typedef unsigned short u16;
typedef short bf16x8 __attribute__((ext_vector_type(8)));
typedef float f32x4 __attribute__((ext_vector_type(4)));

#define DEVI static __device__ __forceinline__

#if __has_builtin(__builtin_amdgcn_exp2f)
#define EXP2F(x) __builtin_amdgcn_exp2f(x)
#else
#define EXP2F(x) exp2f(x)
#endif

DEVI u16 f2bf(float f) {
  union { float f; uint32_t u; } v; v.f = f;
  uint32_t u = v.u;
  u += 0x7fffu + ((u >> 16) & 1u);   // round-to-nearest-even
  return (u16)(u >> 16);
}
DEVI uint32_t pk2bf(float lo, float hi) {
  __hip_bfloat162 h = __float22bfloat162_rn(float2{lo, hi});
  union { __hip_bfloat162 h; uint32_t u; } v; v.h = h; return v.u;
}

DEVI void async16(const void* g, const void* l) {
  __builtin_amdgcn_global_load_lds(
      (const __attribute__((address_space(1))) void*)g,
      (__attribute__((address_space(3))) void*)l, 16, 0, 0);
}

DEVI f32x4 mfma16(bf16x8 a, bf16x8 b, f32x4 c) {
  return __builtin_amdgcn_mfma_f32_16x16x32_bf16(a, b, c, 0, 0, 0);
}

// ---------------------------------------------------------------- constants
// B=2, S=2048, H=1024, NH=16, D=64, M=B*S=4096
// log2(e)/sqrt(64): folded into Q at the qkv epilogue
#define CSC 0.18033688011112042f

// ------------------------------------------------- kernel 1: fp32 -> bf16 x
__global__ void convx(const float* __restrict__ q, const float* __restrict__ k,
                      const float* __restrict__ v, u16* __restrict__ out) {
  const int z = blockIdx.y;
  const float* src = (z == 0) ? q : (z == 1) ? k : v;
  const int i = (blockIdx.x * 256 + threadIdx.x) * 4;
  float4 f = *(const float4*)(src + i);
  ushort4 o;
  o.x = f2bf(f.x); o.y = f2bf(f.y); o.z = f2bf(f.z); o.w = f2bf(f.w);
  *(ushort4*)(out + (size_t)z * 4194304 + i) = o;
}

// ----------------------------------- kernel 2: W[k][n] -> Wt[n][k] in bf16
__global__ void transw(const float* __restrict__ Wq, const float* __restrict__ Wk,
                       const float* __restrict__ Wv, const float* __restrict__ Wo,
                       u16* __restrict__ WT) {
  __shared__ u16 tile[64 * 68];
  const int z = blockIdx.z;
  const float* W = (z == 0) ? Wq : (z == 1) ? Wk : (z == 2) ? Wv : Wo;
  u16* out = WT + (size_t)z * 1048576;
  const int R0 = blockIdx.y * 64, C0 = blockIdx.x * 64;
  const int t = threadIdx.x;
#pragma unroll
  for (int it = 0; it < 16; ++it) {
    int j = it * 256 + t;
    int r = j >> 6, c = j & 63;
    tile[r * 68 + c] = f2bf(W[(size_t)(R0 + r) * 1024 + C0 + c]);
  }
  __syncthreads();
#pragma unroll
  for (int it = 0; it < 16; ++it) {
    int j = it * 256 + t;
    int c = j >> 6, r = j & 63;
    out[(size_t)(C0 + c) * 1024 + R0 + r] = tile[r * 68 + c];
  }
}

// -------------------------------------------------- fused QKV projection GEMM
// BK=64, 16 k-iters, uniform C^T orientation (regs = n = d-dim) for ALL z.
// Epilogue bounces acc through LDS so every global store is a 256B-contiguous
// run (full-line coverage). z=0: Q natural [b,s,1024] pre-scaled by CSC;
// z=1: K natural [b,s,1024]; z=2: V^T [b,h,d,s].
// XCD swizzle: 1-D grid of 256 tiles, m_tile = T&31 -> same-A-stripe blocks
// share an XCD (xcd = T%8 = m%8); per-XCD: 4 A-stripes + full B = 3MB < 4MB L2.
__global__ __launch_bounds__(256, 3)
void qkv_gemm(const u16* __restrict__ XB, const u16* __restrict__ WT,
              const float* __restrict__ bq, const float* __restrict__ bk,
              const float* __restrict__ bv,
              u16* __restrict__ QN, u16* __restrict__ KN, u16* __restrict__ VT) {
  __shared__ u16 smem[16896];          // lA(8192) + lB(8192); reused as 128x132 bounce
  u16* lA = smem;
  u16* lB = smem + 8192;
  const int z = blockIdx.y;
  const u16* A  = XB + (size_t)z * 4194304;
  const u16* Bt = WT + (size_t)z * 1048576;
  const float* bias = (z == 0) ? bq : (z == 1) ? bk : bv;
  const int T = blockIdx.x;
  const int m0 = (T & 31) * 128, n0 = (T >> 5) * 128;
  const int t = threadIdx.x, lane = t & 63, w = t >> 6;
  const int quad = lane >> 4, l16 = lane & 15;
  const int wm = (w & 1) * 64, wn = (w >> 1) * 64;

  f32x4 acc[4][4] = {};
  for (int kt = 0; kt < 16; ++kt) {
    const int k0 = kt * 64;
#pragma unroll
    for (int it = 0; it < 4; ++it) {
      int i = it * 256 + t;
      int r = i >> 3, cc = i & 7, c = cc ^ (r & 7);
      async16(A + (size_t)(m0 + r) * 1024 + k0 + c * 8, &lA[i * 8]);
      async16(Bt + (size_t)(n0 + r) * 1024 + k0 + c * 8, &lB[i * 8]);
    }
    __syncthreads();
#pragma unroll
    for (int ks = 0; ks < 2; ++ks) {
      bf16x8 af[4], bfr[4];
#pragma unroll
      for (int rt = 0; rt < 4; ++rt) {
        int row = wm + rt * 16 + l16;
        af[rt] = *(const bf16x8*)&lA[row * 64 + ((ks * 4 + quad) ^ (row & 7)) * 8];
      }
#pragma unroll
      for (int ct = 0; ct < 4; ++ct) {
        int row = wn + ct * 16 + l16;
        bfr[ct] = *(const bf16x8*)&lB[row * 64 + ((ks * 4 + quad) ^ (row & 7)) * 8];
      }
#pragma unroll
      for (int rt = 0; rt < 4; ++rt)
#pragma unroll
        for (int ct = 0; ct < 4; ++ct)
          acc[rt][ct] = mfma16(bfr[ct], af[rt], acc[rt][ct]);  // C^T: regs = d
    }
    __syncthreads();
  }

  // ---- epilogue via LDS bounce (all waves past final barrier; smem reusable)
  if (z < 2) {
    const float scl = (z == 0) ? CSC : 1.0f;
    // acc -> smem[s][132 + d]  (s-local = wm+rt*16+l16, d-local = wn+ct*16+quad*4)
#pragma unroll
    for (int rt = 0; rt < 4; ++rt) {
      int sl = wm + rt * 16 + l16;
#pragma unroll
      for (int ct = 0; ct < 4; ++ct) {
        int nb = wn + ct * 16 + quad * 4;
        float4 b4 = *(const float4*)&bias[n0 + nb];
        ushort4 pk;
        pk.x = f2bf((acc[rt][ct][0] + b4.x) * scl);
        pk.y = f2bf((acc[rt][ct][1] + b4.y) * scl);
        pk.z = f2bf((acc[rt][ct][2] + b4.z) * scl);
        pk.w = f2bf((acc[rt][ct][3] + b4.w) * scl);
        *(ushort4*)&smem[sl * 132 + nb] = pk;
      }
    }
    __syncthreads();
    // coalesced store: natural [4096][1024]; 256B-contiguous per 16 lanes
    u16* out = (z == 0) ? QN : KN;
#pragma unroll
    for (int p = 0; p < 8; ++p) {
      int idx = p * 256 + t;
      int row = idx >> 4, chunk = idx & 15;
      *(bf16x8*)&out[(size_t)(m0 + row) * 1024 + n0 + chunk * 8] =
          *(const bf16x8*)&smem[row * 132 + chunk * 8];
    }
  } else {
    // acc -> smem[d][132 + s] (transpose via scalar LDS writes)
#pragma unroll
    for (int rt = 0; rt < 4; ++rt) {
      int sl = wm + rt * 16 + l16;
#pragma unroll
      for (int ct = 0; ct < 4; ++ct) {
        int nb = wn + ct * 16 + quad * 4;
        float4 b4 = *(const float4*)&bias[n0 + nb];
        smem[(nb + 0) * 132 + sl] = f2bf(acc[rt][ct][0] + b4.x);
        smem[(nb + 1) * 132 + sl] = f2bf(acc[rt][ct][1] + b4.y);
        smem[(nb + 2) * 132 + sl] = f2bf(acc[rt][ct][2] + b4.z);
        smem[(nb + 3) * 132 + sl] = f2bf(acc[rt][ct][3] + b4.w);
      }
    }
    __syncthreads();
    // coalesced store: VT[b,h,d,s]; 256B-contiguous per 16 lanes
    const int bb = m0 >> 11, sb = m0 & 2047;
#pragma unroll
    for (int p = 0; p < 8; ++p) {
      int idx = p * 256 + t;
      int dl = idx >> 4, chunk = idx & 15;
      int ncol = n0 + dl, hh = ncol >> 6, dd = ncol & 63;
      *(bf16x8*)&VT[((size_t)((bb * 16 + hh) * 64 + dd)) * 2048 + sb + chunk * 8] =
          *(const bf16x8*)&smem[dl * 132 + chunk * 8];
    }
  }
}

// -------------------------------------------------------- flash attention
// attn8: attn5's proven shape (512 thr, 8 waves x 16 q, grid (16,16,2),
// 2 blocks/CU, 16 waves/CU — R0-R3 showed perf tracks waves/CU) with the
// P LDS round-trip ELIMINATED via K-row permutation:
//   PV's B-frag needs lane(quad,l16) to hold P[32ks2+8quad+j]; QK^T leaves
//   it holding P[16st+4quad+r]. These differ by a bit-permutation sigma of
//   the sk axis (bit4<-bit3, bit3<-bit2, bit2<-bit4). Applying sigma to the
//   K STAGING SOURCE ROW (whole-row permute, 16B chunks stay contiguous,
//   zero cost) makes the post-exp registers directly usable as the PV
//   fragment: pf(ks2) = pack(sc[2ks2], sc[2ks2+1]). V stays linear; lsum
//   still covers a bijective set. Deletes 4 ds_write_b64 + 2 ds_read_b128
//   + the write->read chain per wave per tile, all P bank conflicts, and
//   18 KB LDS (total now 32 KB).
__global__ __launch_bounds__(512, 4)
void attn8(const u16* __restrict__ QN, const u16* __restrict__ KN,
           const u16* __restrict__ VT, u16* __restrict__ AO) {
  __shared__ u16 lK[2][64 * 64];
  __shared__ u16 lV[2][64 * 64];
  const int qt0 = blockIdx.x, h = blockIdx.y, b = blockIdx.z;
  const int t = threadIdx.x, lane = t & 63, w = t >> 6;
  const int quad = lane >> 4, l16 = lane & 15;
  const u16* Qg = QN + ((size_t)(b * 2048 + qt0 * 128)) * 1024 + h * 64;
  const u16* Kg = KN + ((size_t)b * 2048) * 1024 + h * 64;
  const u16* Vg = VT + ((size_t)((b * 16 + h) * 64)) * 2048;

  // sigma(r): bit4<-bit3, bit3<-bit2, bit2<-bit4 (bits 5,1,0 fixed)
  const int sr_r = t >> 3;  // LDS row this thread stages
  const int sg_r = (sr_r & 0x23) | ((sr_r & 8) << 1) | ((sr_r & 4) << 1) |
                   ((sr_r & 16) >> 2);
  const int sc_c = (t & 7) ^ (sr_r & 7);  // pre-swizzled source chunk

  // Q fragments straight from global (pre-scaled by CSC in qkv_gemm)
  bf16x8 qf[2];
#pragma unroll
  for (int ks = 0; ks < 2; ++ks)
    qf[ks] = *(const bf16x8*)(Qg + (size_t)(w * 16 + l16) * 1024 + ks * 32 + quad * 8);

  // stage tile 0: K rows sigma-permuted (natural K, stride 1024), V rows linear
  async16(Kg + (size_t)sg_r * 1024 + sc_c * 8, &lK[0][t * 8]);
  async16(Vg + (size_t)sr_r * 2048 + sc_c * 8, &lV[0][t * 8]);
  __syncthreads();

  f32x4 o[4] = {};
  float lsum = 0.f;

  for (int kt = 0; kt < 32; ++kt) {
    const int cur = kt & 1, nxt = cur ^ 1;
    if (kt + 1 < 32) {
      const int kb = (kt + 1) * 64;
      async16(Kg + (size_t)(kb + sg_r) * 1024 + sc_c * 8, &lK[nxt][t * 8]);
      async16(Vg + (size_t)sr_r * 2048 + kb + sc_c * 8, &lV[nxt][t * 8]);
    }

    // ---- QK^T -> S^T (sigma-permuted rows): lane holds sk'=16st+4quad+r
    f32x4 sc[4];
    __builtin_amdgcn_s_setprio(1);
#pragma unroll
    for (int st = 0; st < 4; ++st) {
      int row = st * 16 + l16;
      bf16x8 kf0 = *(const bf16x8*)&lK[cur][row * 64 + ((quad) ^ (row & 7)) * 8];
      bf16x8 kf1 = *(const bf16x8*)&lK[cur][row * 64 + ((4 + quad) ^ (row & 7)) * 8];
      f32x4 z = {};
      sc[st] = mfma16(kf0, qf[0], z);
      sc[st] = mfma16(kf1, qf[1], sc[st]);
    }
    __builtin_amdgcn_s_setprio(0);

    // ---- p = exp2(s); lsum; pack directly into PV fragments (no LDS!)
    uint32_t pw[8];
#pragma unroll
    for (int st = 0; st < 4; ++st) {
      float p0 = EXP2F(sc[st][0]);
      float p1 = EXP2F(sc[st][1]);
      float p2 = EXP2F(sc[st][2]);
      float p3 = EXP2F(sc[st][3]);
      lsum += (p0 + p1) + (p2 + p3);
      pw[st * 2 + 0] = pk2bf(p0, p1);
      pw[st * 2 + 1] = pk2bf(p2, p3);
    }
    union { uint32_t u[4]; bf16x8 v; } pf0c, pf1c;
    pf0c.u[0] = pw[0]; pf0c.u[1] = pw[1]; pf0c.u[2] = pw[2]; pf0c.u[3] = pw[3];
    pf1c.u[0] = pw[4]; pf1c.u[1] = pw[5]; pf1c.u[2] = pw[6]; pf1c.u[3] = pw[7];

    // ---- PV: O^T += V^T(64d x 64sk) * P(16q x 64sk), P from registers
    __builtin_amdgcn_s_setprio(1);
#pragma unroll
    for (int dt = 0; dt < 4; ++dt) {
      int row = dt * 16 + l16;
      bf16x8 vf0 = *(const bf16x8*)&lV[cur][row * 64 + ((quad) ^ (row & 7)) * 8];
      bf16x8 vf1 = *(const bf16x8*)&lV[cur][row * 64 + ((4 + quad) ^ (row & 7)) * 8];
      o[dt] = mfma16(vf0, pf0c.v, o[dt]);
      o[dt] = mfma16(vf1, pf1c.v, o[dt]);
    }
    __builtin_amdgcn_s_setprio(0);
    __syncthreads();
  }

  // ---- epilogue: O^T/l -> AO [b][s][h*64+d] bf16 (4 consecutive d per lane)
  float l = lsum;
  l += __shfl_xor(l, 16, 64);
  l += __shfl_xor(l, 32, 64);
  float inv = 1.0f / l;
  int qglob = qt0 * 128 + w * 16 + l16;
  size_t base = ((size_t)(b * 2048 + qglob)) * 1024 + h * 64;
#pragma unroll
  for (int dt = 0; dt < 4; ++dt) {
    ushort4 pk;
    pk.x = f2bf(o[dt][0] * inv);
    pk.y = f2bf(o[dt][1] * inv);
    pk.z = f2bf(o[dt][2] * inv);
    pk.w = f2bf(o[dt][3] * inv);
    *(ushort4*)&AO[base + dt * 16 + quad * 4] = pk;
  }
}

// ------------------------------------------------------- output projection
// 128m x 64n tiles, BK=64, 512 blocks, XCD swizzle (m_tile = T&31).
// Normal orientation; scalar f32 stores = 64B runs (R3-style, known-good).
__global__ __launch_bounds__(256, 2)
void oproj_gemm(const u16* __restrict__ AO, const u16* __restrict__ Bt,
                const float* __restrict__ bias, float* __restrict__ out) {
  __shared__ u16 lA[128 * 64];
  __shared__ u16 lB[64 * 64];
  const int T = blockIdx.x;
  const int m0 = (T & 31) * 128, n0 = (T >> 5) * 64;
  const int t = threadIdx.x, lane = t & 63, w = t >> 6;
  const int quad = lane >> 4, l16 = lane & 15;
  const int wm = (w & 1) * 64, wn = (w >> 1) * 32;

  f32x4 acc[4][2] = {};
  for (int kt = 0; kt < 16; ++kt) {
    const int k0 = kt * 64;
#pragma unroll
    for (int it = 0; it < 4; ++it) {
      int i = it * 256 + t;
      int r = i >> 3, cc = i & 7, c = cc ^ (r & 7);
      async16(AO + (size_t)(m0 + r) * 1024 + k0 + c * 8, &lA[i * 8]);
    }
#pragma unroll
    for (int it = 0; it < 2; ++it) {
      int i = it * 256 + t;
      int r = i >> 3, cc = i & 7, c = cc ^ (r & 7);
      async16(Bt + (size_t)(n0 + r) * 1024 + k0 + c * 8, &lB[i * 8]);
    }
    __syncthreads();
#pragma unroll
    for (int ks = 0; ks < 2; ++ks) {
      bf16x8 af[4], bfr[2];
#pragma unroll
      for (int rt = 0; rt < 4; ++rt) {
        int row = wm + rt * 16 + l16;
        af[rt] = *(const bf16x8*)&lA[row * 64 + ((ks * 4 + quad) ^ (row & 7)) * 8];
      }
#pragma unroll
      for (int ct = 0; ct < 2; ++ct) {
        int row = wn + ct * 16 + l16;
        bfr[ct] = *(const bf16x8*)&lB[row * 64 + ((ks * 4 + quad) ^ (row & 7)) * 8];
      }
#pragma unroll
      for (int rt = 0; rt < 4; ++rt)
#pragma unroll
        for (int ct = 0; ct < 2; ++ct)
          acc[rt][ct] = mfma16(af[rt], bfr[ct], acc[rt][ct]);
    }
    __syncthreads();
  }

#pragma unroll
  for (int ct = 0; ct < 2; ++ct) {
    int ncol = n0 + wn + ct * 16 + l16;
    float bvv = bias[ncol];
#pragma unroll
    for (int rt = 0; rt < 4; ++rt)
#pragma unroll
      for (int r = 0; r < 4; ++r) {
        int m = m0 + wm + rt * 16 + quad * 4 + r;
        out[(size_t)m * 1024 + ncol] = acc[rt][ct][r] + bvv;
      }
  }
}

// ------------------------------------------------------------------ launch
extern "C" void kernel_launch(void* const* d_in, const int* in_sizes, int n_in,
                              void* d_out, int out_size, void* d_ws, size_t ws_size,
                              hipStream_t stream) {
  const float* query = (const float*)d_in[0];
  const float* key   = (const float*)d_in[1];
  const float* value = (const float*)d_in[2];
  const float* Wq = (const float*)d_in[3];
  const float* bq = (const float*)d_in[4];
  const float* Wk = (const float*)d_in[5];
  const float* bk = (const float*)d_in[6];
  const float* Wv = (const float*)d_in[7];
  const float* bv = (const float*)d_in[8];
  const float* Wo = (const float*)d_in[9];
  const float* bo = (const float*)d_in[10];
  float* out = (float*)d_out;

  // workspace layout (u16 elements): total 28M u16 = 56 MB
  u16* WT = (u16*)d_ws;              // 4 x 1M  (Wq_t, Wk_t, Wv_t, Wo_t)
  u16* QN = WT + 4 * 1048576;        // 4M  natural [b,s,1024] (pre-scaled by CSC)
  u16* KN = QN + 4194304;            // 4M  natural [b,s,1024]
  u16* VT = KN + 4194304;            // 4M  [b,h,d,s]
  u16* XB = VT + 4194304;            // 3 x 4M bf16 copies of q,k,v
  u16* AO = XB;                      // attn out aliases XB (dead by then)

  convx<<<dim3(4096, 3), 256, 0, stream>>>(query, key, value, XB);
  transw<<<dim3(16, 16, 4), 256, 0, stream>>>(Wq, Wk, Wv, Wo, WT);
  qkv_gemm<<<dim3(256, 3), 256, 0, stream>>>(XB, WT, bq, bk, bv, QN, KN, VT);
  attn8<<<dim3(16, 16, 2), 512, 0, stream>>>(QN, KN, VT, AO);
  oproj_gemm<<<dim3(512), 256, 0, stream>>>(AO, WT + 3 * 1048576, bo, out);
}

// Round 6
// 208.228 us; speedup vs baseline: 1.1605x; 1.0343x over previous
//
#include <hip/hip_runtime.h>
#include <hip/hip_bf16.h>
#include <stdint.h>

typedef unsigned short u16;
typedef short bf16x8 __attribute__((ext_vector_type(8)));
typedef float f32x4 __attribute__((ext_vector_type(4)));

#define DEVI static __device__ __forceinline__

#if __has_builtin(__builtin_amdgcn_exp2f)
#define EXP2F(x) __builtin_amdgcn_exp2f(x)
#else
#define EXP2F(x) exp2f(x)
#endif

DEVI u16 f2bf(float f) {
  union { float f; uint32_t u; } v; v.f = f;
  uint32_t u = v.u;
  u += 0x7fffu + ((u >> 16) & 1u);   // round-to-nearest-even
  return (u16)(u >> 16);
}
DEVI uint32_t pk2bf(float lo, float hi) {
  __hip_bfloat162 h = __float22bfloat162_rn(float2{lo, hi});
  union { __hip_bfloat162 h; uint32_t u; } v; v.h = h; return v.u;
}

DEVI void async16(const void* g, const void* l) {
  __builtin_amdgcn_global_load_lds(
      (const __attribute__((address_space(1))) void*)g,
      (__attribute__((address_space(3))) void*)l, 16, 0, 0);
}

DEVI f32x4 mfma16(bf16x8 a, bf16x8 b, f32x4 c) {
  return __builtin_amdgcn_mfma_f32_16x16x32_bf16(a, b, c, 0, 0, 0);
}

// ---------------------------------------------------------------- constants
// B=2, S=2048, H=1024, NH=16, D=64, M=B*S=4096
// log2(e)/sqrt(64): folded into Q at the qkv epilogue
#define CSC 0.18033688011112042f

// ------------------------------------------------- kernel 1: fp32 -> bf16 x
__global__ void convx(const float* __restrict__ q, const float* __restrict__ k,
                      const float* __restrict__ v, u16* __restrict__ out) {
  const int z = blockIdx.y;
  const float* src = (z == 0) ? q : (z == 1) ? k : v;
  const int i = (blockIdx.x * 256 + threadIdx.x) * 4;
  float4 f = *(const float4*)(src + i);
  ushort4 o;
  o.x = f2bf(f.x); o.y = f2bf(f.y); o.z = f2bf(f.z); o.w = f2bf(f.w);
  *(ushort4*)(out + (size_t)z * 4194304 + i) = o;
}

// ----------------------------------- kernel 2: W[k][n] -> Wt[n][k] in bf16
__global__ void transw(const float* __restrict__ Wq, const float* __restrict__ Wk,
                       const float* __restrict__ Wv, const float* __restrict__ Wo,
                       u16* __restrict__ WT) {
  __shared__ u16 tile[64 * 68];
  const int z = blockIdx.z;
  const float* W = (z == 0) ? Wq : (z == 1) ? Wk : (z == 2) ? Wv : Wo;
  u16* out = WT + (size_t)z * 1048576;
  const int R0 = blockIdx.y * 64, C0 = blockIdx.x * 64;
  const int t = threadIdx.x;
#pragma unroll
  for (int it = 0; it < 16; ++it) {
    int j = it * 256 + t;
    int r = j >> 6, c = j & 63;
    tile[r * 68 + c] = f2bf(W[(size_t)(R0 + r) * 1024 + C0 + c]);
  }
  __syncthreads();
#pragma unroll
  for (int it = 0; it < 16; ++it) {
    int j = it * 256 + t;
    int c = j >> 6, r = j & 63;
    out[(size_t)(C0 + c) * 1024 + R0 + r] = tile[r * 68 + c];
  }
}

// -------------------------------------------------- fused QKV projection GEMM
// BK=64, 16 k-iters, uniform C^T orientation (regs = n = d-dim) for ALL z.
// Epilogue bounces acc through LDS so every global store is a 256B-contiguous
// run (full-line coverage). z=0: Q natural [b,s,1024] pre-scaled by CSC;
// z=1: K natural [b,s,1024]; z=2: V^T [b,h,d,s].
// XCD swizzle: 1-D grid of 256 tiles, m_tile = T&31 -> same-A-stripe blocks
// share an XCD (xcd = T%8 = m%8); per-XCD: 4 A-stripes + full B = 3MB < 4MB L2.
__global__ __launch_bounds__(256, 3)
void qkv_gemm(const u16* __restrict__ XB, const u16* __restrict__ WT,
              const float* __restrict__ bq, const float* __restrict__ bk,
              const float* __restrict__ bv,
              u16* __restrict__ QN, u16* __restrict__ KN, u16* __restrict__ VT) {
  __shared__ u16 smem[16896];          // lA(8192) + lB(8192); reused as 128x132 bounce
  u16* lA = smem;
  u16* lB = smem + 8192;
  const int z = blockIdx.y;
  const u16* A  = XB + (size_t)z * 4194304;
  const u16* Bt = WT + (size_t)z * 1048576;
  const float* bias = (z == 0) ? bq : (z == 1) ? bk : bv;
  const int T = blockIdx.x;
  const int m0 = (T & 31) * 128, n0 = (T >> 5) * 128;
  const int t = threadIdx.x, lane = t & 63, w = t >> 6;
  const int quad = lane >> 4, l16 = lane & 15;
  const int wm = (w & 1) * 64, wn = (w >> 1) * 64;

  f32x4 acc[4][4] = {};
  for (int kt = 0; kt < 16; ++kt) {
    const int k0 = kt * 64;
#pragma unroll
    for (int it = 0; it < 4; ++it) {
      int i = it * 256 + t;
      int r = i >> 3, cc = i & 7, c = cc ^ (r & 7);
      async16(A + (size_t)(m0 + r) * 1024 + k0 + c * 8, &lA[i * 8]);
      async16(Bt + (size_t)(n0 + r) * 1024 + k0 + c * 8, &lB[i * 8]);
    }
    __syncthreads();
#pragma unroll
    for (int ks = 0; ks < 2; ++ks) {
      bf16x8 af[4], bfr[4];
#pragma unroll
      for (int rt = 0; rt < 4; ++rt) {
        int row = wm + rt * 16 + l16;
        af[rt] = *(const bf16x8*)&lA[row * 64 + ((ks * 4 + quad) ^ (row & 7)) * 8];
      }
#pragma unroll
      for (int ct = 0; ct < 4; ++ct) {
        int row = wn + ct * 16 + l16;
        bfr[ct] = *(const bf16x8*)&lB[row * 64 + ((ks * 4 + quad) ^ (row & 7)) * 8];
      }
#pragma unroll
      for (int rt = 0; rt < 4; ++rt)
#pragma unroll
        for (int ct = 0; ct < 4; ++ct)
          acc[rt][ct] = mfma16(bfr[ct], af[rt], acc[rt][ct]);  // C^T: regs = d
    }
    __syncthreads();
  }

  // ---- epilogue via LDS bounce (all waves past final barrier; smem reusable)
  if (z < 2) {
    const float scl = (z == 0) ? CSC : 1.0f;
    // acc -> smem[s][132 + d]  (s-local = wm+rt*16+l16, d-local = wn+ct*16+quad*4)
#pragma unroll
    for (int rt = 0; rt < 4; ++rt) {
      int sl = wm + rt * 16 + l16;
#pragma unroll
      for (int ct = 0; ct < 4; ++ct) {
        int nb = wn + ct * 16 + quad * 4;
        float4 b4 = *(const float4*)&bias[n0 + nb];
        ushort4 pk;
        pk.x = f2bf((acc[rt][ct][0] + b4.x) * scl);
        pk.y = f2bf((acc[rt][ct][1] + b4.y) * scl);
        pk.z = f2bf((acc[rt][ct][2] + b4.z) * scl);
        pk.w = f2bf((acc[rt][ct][3] + b4.w) * scl);
        *(ushort4*)&smem[sl * 132 + nb] = pk;
      }
    }
    __syncthreads();
    // coalesced store: natural [4096][1024]; 256B-contiguous per 16 lanes
    u16* out = (z == 0) ? QN : KN;
#pragma unroll
    for (int p = 0; p < 8; ++p) {
      int idx = p * 256 + t;
      int row = idx >> 4, chunk = idx & 15;
      *(bf16x8*)&out[(size_t)(m0 + row) * 1024 + n0 + chunk * 8] =
          *(const bf16x8*)&smem[row * 132 + chunk * 8];
    }
  } else {
    // acc -> smem[d][132 + s] (transpose via scalar LDS writes)
#pragma unroll
    for (int rt = 0; rt < 4; ++rt) {
      int sl = wm + rt * 16 + l16;
#pragma unroll
      for (int ct = 0; ct < 4; ++ct) {
        int nb = wn + ct * 16 + quad * 4;
        float4 b4 = *(const float4*)&bias[n0 + nb];
        smem[(nb + 0) * 132 + sl] = f2bf(acc[rt][ct][0] + b4.x);
        smem[(nb + 1) * 132 + sl] = f2bf(acc[rt][ct][1] + b4.y);
        smem[(nb + 2) * 132 + sl] = f2bf(acc[rt][ct][2] + b4.z);
        smem[(nb + 3) * 132 + sl] = f2bf(acc[rt][ct][3] + b4.w);
      }
    }
    __syncthreads();
    // coalesced store: VT[b,h,d,s]; 256B-contiguous per 16 lanes
    const int bb = m0 >> 11, sb = m0 & 2047;
#pragma unroll
    for (int p = 0; p < 8; ++p) {
      int idx = p * 256 + t;
      int dl = idx >> 4, chunk = idx & 15;
      int ncol = n0 + dl, hh = ncol >> 6, dd = ncol & 63;
      *(bf16x8*)&VT[((size_t)((bb * 16 + hh) * 64 + dd)) * 2048 + sb + chunk * 8] =
          *(const bf16x8*)&smem[dl * 132 + chunk * 8];
    }
  }
}

// -------------------------------------------------------- flash attention
// attn9 = attn8 (55.0us, VALUBusy 43% vs MfmaUtil 25% -> VALU-bound on
// softmax bookkeeping) with lsum MOVED TO THE MFMA PIPE:
//   row-sum of P is rank-1: ones^T * P. Accumulate ls = mfma16(ones, pf, ls)
//   (2 extra MFMAs/tile on the 25%-busy matrix pipe) and delete ~14 VALU
//   adds/tile + both epilogue shuffles (ls[0] already holds the full row
//   sum in every lane). Denominator now sums the same bf16-rounded p the
//   PV numerator uses (more self-consistent).
// Keeps attn8's sigma-permuted K staging (PV's P-operand comes straight
// from post-exp registers, no P LDS round-trip), 512 thr / 8 waves x 16 q,
// grid (16,16,2), 2 blocks/CU, double-buffered K/V, one barrier/tile.
__global__ __launch_bounds__(512, 4)
void attn9(const u16* __restrict__ QN, const u16* __restrict__ KN,
           const u16* __restrict__ VT, u16* __restrict__ AO) {
  __shared__ u16 lK[2][64 * 64];
  __shared__ u16 lV[2][64 * 64];
  const int qt0 = blockIdx.x, h = blockIdx.y, b = blockIdx.z;
  const int t = threadIdx.x, lane = t & 63, w = t >> 6;
  const int quad = lane >> 4, l16 = lane & 15;
  const u16* Qg = QN + ((size_t)(b * 2048 + qt0 * 128)) * 1024 + h * 64;
  const u16* Kg = KN + ((size_t)b * 2048) * 1024 + h * 64;
  const u16* Vg = VT + ((size_t)((b * 16 + h) * 64)) * 2048;

  // sigma(r): bit4<-bit3, bit3<-bit2, bit2<-bit4 (bits 5,1,0 fixed)
  const int sr_r = t >> 3;  // LDS row this thread stages
  const int sg_r = (sr_r & 0x23) | ((sr_r & 8) << 1) | ((sr_r & 4) << 1) |
                   ((sr_r & 16) >> 2);
  const int sc_c = (t & 7) ^ (sr_r & 7);  // pre-swizzled source chunk

  // Q fragments straight from global (pre-scaled by CSC in qkv_gemm)
  bf16x8 qf[2];
#pragma unroll
  for (int ks = 0; ks < 2; ++ks)
    qf[ks] = *(const bf16x8*)(Qg + (size_t)(w * 16 + l16) * 1024 + ks * 32 + quad * 8);

  // bf16 1.0 x8 (A-operand of the ones-MFMA row-sum)
  const bf16x8 ones = {0x3F80, 0x3F80, 0x3F80, 0x3F80,
                       0x3F80, 0x3F80, 0x3F80, 0x3F80};

  // stage tile 0: K rows sigma-permuted (natural K, stride 1024), V rows linear
  async16(Kg + (size_t)sg_r * 1024 + sc_c * 8, &lK[0][t * 8]);
  async16(Vg + (size_t)sr_r * 2048 + sc_c * 8, &lV[0][t * 8]);
  __syncthreads();

  f32x4 o[4] = {};
  f32x4 ls = {};   // ls[0] accumulates sum_sk P[sk][q=l16] via ones-MFMA

  for (int kt = 0; kt < 32; ++kt) {
    const int cur = kt & 1, nxt = cur ^ 1;
    if (kt + 1 < 32) {
      const int kb = (kt + 1) * 64;
      async16(Kg + (size_t)(kb + sg_r) * 1024 + sc_c * 8, &lK[nxt][t * 8]);
      async16(Vg + (size_t)sr_r * 2048 + kb + sc_c * 8, &lV[nxt][t * 8]);
    }

    // ---- QK^T -> S^T (sigma-permuted rows): lane holds sk'=16st+4quad+r
    f32x4 sc[4];
    __builtin_amdgcn_s_setprio(1);
#pragma unroll
    for (int st = 0; st < 4; ++st) {
      int row = st * 16 + l16;
      bf16x8 kf0 = *(const bf16x8*)&lK[cur][row * 64 + ((quad) ^ (row & 7)) * 8];
      bf16x8 kf1 = *(const bf16x8*)&lK[cur][row * 64 + ((4 + quad) ^ (row & 7)) * 8];
      f32x4 z = {};
      sc[st] = mfma16(kf0, qf[0], z);
      sc[st] = mfma16(kf1, qf[1], sc[st]);
    }
    __builtin_amdgcn_s_setprio(0);

    // ---- p = exp2(s); pack directly into PV fragments (no LDS, no VALU sum)
    union { uint32_t u[4]; bf16x8 v; } pf0c, pf1c;
#pragma unroll
    for (int st = 0; st < 2; ++st) {
      pf0c.u[st * 2 + 0] = pk2bf(EXP2F(sc[st][0]), EXP2F(sc[st][1]));
      pf0c.u[st * 2 + 1] = pk2bf(EXP2F(sc[st][2]), EXP2F(sc[st][3]));
      pf1c.u[st * 2 + 0] = pk2bf(EXP2F(sc[2 + st][0]), EXP2F(sc[2 + st][1]));
      pf1c.u[st * 2 + 1] = pk2bf(EXP2F(sc[2 + st][2]), EXP2F(sc[2 + st][3]));
    }

    // ---- PV: O^T += V^T(64d x 64sk) * P(16q x 64sk), P from registers.
    //      Row-sum on the MFMA pipe: ls += ones^T * P.
    __builtin_amdgcn_s_setprio(1);
    ls = mfma16(ones, pf0c.v, ls);
    ls = mfma16(ones, pf1c.v, ls);
#pragma unroll
    for (int dt = 0; dt < 4; ++dt) {
      int row = dt * 16 + l16;
      bf16x8 vf0 = *(const bf16x8*)&lV[cur][row * 64 + ((quad) ^ (row & 7)) * 8];
      bf16x8 vf1 = *(const bf16x8*)&lV[cur][row * 64 + ((4 + quad) ^ (row & 7)) * 8];
      o[dt] = mfma16(vf0, pf0c.v, o[dt]);
      o[dt] = mfma16(vf1, pf1c.v, o[dt]);
    }
    __builtin_amdgcn_s_setprio(0);
    __syncthreads();
  }

  // ---- epilogue: O^T/l -> AO [b][s][h*64+d] bf16 (4 consecutive d per lane)
  // ls[0] holds the complete row sum for q=l16 in EVERY lane (ones-matrix
  // rows are identical) -> no cross-lane reduction needed.
  float inv = 1.0f / ls[0];
  int qglob = qt0 * 128 + w * 16 + l16;
  size_t base = ((size_t)(b * 2048 + qglob)) * 1024 + h * 64;
#pragma unroll
  for (int dt = 0; dt < 4; ++dt) {
    ushort4 pk;
    pk.x = f2bf(o[dt][0] * inv);
    pk.y = f2bf(o[dt][1] * inv);
    pk.z = f2bf(o[dt][2] * inv);
    pk.w = f2bf(o[dt][3] * inv);
    *(ushort4*)&AO[base + dt * 16 + quad * 4] = pk;
  }
}

// ------------------------------------------------------- output projection
// 128m x 64n tiles, BK=64, 512 blocks, XCD swizzle (m_tile = T&31).
// Normal orientation; scalar f32 stores = 64B runs (R3-style, known-good).
__global__ __launch_bounds__(256, 2)
void oproj_gemm(const u16* __restrict__ AO, const u16* __restrict__ Bt,
                const float* __restrict__ bias, float* __restrict__ out) {
  __shared__ u16 lA[128 * 64];
  __shared__ u16 lB[64 * 64];
  const int T = blockIdx.x;
  const int m0 = (T & 31) * 128, n0 = (T >> 5) * 64;
  const int t = threadIdx.x, lane = t & 63, w = t >> 6;
  const int quad = lane >> 4, l16 = lane & 15;
  const int wm = (w & 1) * 64, wn = (w >> 1) * 32;

  f32x4 acc[4][2] = {};
  for (int kt = 0; kt < 16; ++kt) {
    const int k0 = kt * 64;
#pragma unroll
    for (int it = 0; it < 4; ++it) {
      int i = it * 256 + t;
      int r = i >> 3, cc = i & 7, c = cc ^ (r & 7);
      async16(AO + (size_t)(m0 + r) * 1024 + k0 + c * 8, &lA[i * 8]);
    }
#pragma unroll
    for (int it = 0; it < 2; ++it) {
      int i = it * 256 + t;
      int r = i >> 3, cc = i & 7, c = cc ^ (r & 7);
      async16(Bt + (size_t)(n0 + r) * 1024 + k0 + c * 8, &lB[i * 8]);
    }
    __syncthreads();
#pragma unroll
    for (int ks = 0; ks < 2; ++ks) {
      bf16x8 af[4], bfr[2];
#pragma unroll
      for (int rt = 0; rt < 4; ++rt) {
        int row = wm + rt * 16 + l16;
        af[rt] = *(const bf16x8*)&lA[row * 64 + ((ks * 4 + quad) ^ (row & 7)) * 8];
      }
#pragma unroll
      for (int ct = 0; ct < 2; ++ct) {
        int row = wn + ct * 16 + l16;
        bfr[ct] = *(const bf16x8*)&lB[row * 64 + ((ks * 4 + quad) ^ (row & 7)) * 8];
      }
#pragma unroll
      for (int rt = 0; rt < 4; ++rt)
#pragma unroll
        for (int ct = 0; ct < 2; ++ct)
          acc[rt][ct] = mfma16(af[rt], bfr[ct], acc[rt][ct]);
    }
    __syncthreads();
  }

#pragma unroll
  for (int ct = 0; ct < 2; ++ct) {
    int ncol = n0 + wn + ct * 16 + l16;
    float bvv = bias[ncol];
#pragma unroll
    for (int rt = 0; rt < 4; ++rt)
#pragma unroll
      for (int r = 0; r < 4; ++r) {
        int m = m0 + wm + rt * 16 + quad * 4 + r;
        out[(size_t)m * 1024 + ncol] = acc[rt][ct][r] + bvv;
      }
  }
}

// ------------------------------------------------------------------ launch
extern "C" void kernel_launch(void* const* d_in, const int* in_sizes, int n_in,
                              void* d_out, int out_size, void* d_ws, size_t ws_size,
                              hipStream_t stream) {
  const float* query = (const float*)d_in[0];
  const float* key   = (const float*)d_in[1];
  const float* value = (const float*)d_in[2];
  const float* Wq = (const float*)d_in[3];
  const float* bq = (const float*)d_in[4];
  const float* Wk = (const float*)d_in[5];
  const float* bk = (const float*)d_in[6];
  const float* Wv = (const float*)d_in[7];
  const float* bv = (const float*)d_in[8];
  const float* Wo = (const float*)d_in[9];
  const float* bo = (const float*)d_in[10];
  float* out = (float*)d_out;

  // workspace layout (u16 elements): total 28M u16 = 56 MB
  u16* WT = (u16*)d_ws;              // 4 x 1M  (Wq_t, Wk_t, Wv_t, Wo_t)
  u16* QN = WT + 4 * 1048576;        // 4M  natural [b,s,1024] (pre-scaled by CSC)
  u16* KN = QN + 4194304;            // 4M  natural [b,s,1024]
  u16* VT = KN + 4194304;            // 4M  [b,h,d,s]
  u16* XB = VT + 4194304;            // 3 x 4M bf16 copies of q,k,v
  u16* AO = XB;                      // attn out aliases XB (dead by then)

  convx<<<dim3(4096, 3), 256, 0, stream>>>(query, key, value, XB);
  transw<<<dim3(16, 16, 4), 256, 0, stream>>>(Wq, Wk, Wv, Wo, WT);
  qkv_gemm<<<dim3(256, 3), 256, 0, stream>>>(XB, WT, bq, bk, bv, QN, KN, VT);
  attn9<<<dim3(16, 16, 2), 512, 0, stream>>>(QN, KN, VT, AO);
  oproj_gemm<<<dim3(512), 256, 0, stream>>>(AO, WT + 3 * 1048576, bo, out);
}

// Round 7
// 205.093 us; speedup vs baseline: 1.1782x; 1.0153x over previous
//
#include <hip/hip_runtime.h>
#include <hip/hip_bf16.h>
#include <stdint.h>

typedef unsigned short u16;
typedef short bf16x8 __attribute__((ext_vector_type(8)));
typedef float f32x4 __attribute__((ext_vector_type(4)));

#define DEVI static __device__ __forceinline__

#if __has_builtin(__builtin_amdgcn_exp2f)
#define EXP2F(x) __builtin_amdgcn_exp2f(x)
#else
#define EXP2F(x) exp2f(x)
#endif

DEVI u16 f2bf(float f) {
  union { float f; uint32_t u; } v; v.f = f;
  uint32_t u = v.u;
  u += 0x7fffu + ((u >> 16) & 1u);   // round-to-nearest-even
  return (u16)(u >> 16);
}
DEVI uint32_t pk2bf(float lo, float hi) {
  __hip_bfloat162 h = __float22bfloat162_rn(float2{lo, hi});
  union { __hip_bfloat162 h; uint32_t u; } v; v.h = h; return v.u;
}

DEVI void async16(const void* g, const void* l) {
  __builtin_amdgcn_global_load_lds(
      (const __attribute__((address_space(1))) void*)g,
      (__attribute__((address_space(3))) void*)l, 16, 0, 0);
}

DEVI f32x4 mfma16(bf16x8 a, bf16x8 b, f32x4 c) {
  return __builtin_amdgcn_mfma_f32_16x16x32_bf16(a, b, c, 0, 0, 0);
}

// ---------------------------------------------------------------- constants
// B=2, S=2048, H=1024, NH=16, D=64, M=B*S=4096
// log2(e)/sqrt(64): folded into Q at the qkv epilogue
#define CSC 0.18033688011112042f

// ------------------------------------------------- kernel 1: fp32 -> bf16 x
__global__ void convx(const float* __restrict__ q, const float* __restrict__ k,
                      const float* __restrict__ v, u16* __restrict__ out) {
  const int z = blockIdx.y;
  const float* src = (z == 0) ? q : (z == 1) ? k : v;
  const int i = (blockIdx.x * 256 + threadIdx.x) * 4;
  float4 f = *(const float4*)(src + i);
  ushort4 o;
  o.x = f2bf(f.x); o.y = f2bf(f.y); o.z = f2bf(f.z); o.w = f2bf(f.w);
  *(ushort4*)(out + (size_t)z * 4194304 + i) = o;
}

// ----------------------------------- kernel 2: W[k][n] -> Wt[n][k] in bf16
__global__ void transw(const float* __restrict__ Wq, const float* __restrict__ Wk,
                       const float* __restrict__ Wv, const float* __restrict__ Wo,
                       u16* __restrict__ WT) {
  __shared__ u16 tile[64 * 68];
  const int z = blockIdx.z;
  const float* W = (z == 0) ? Wq : (z == 1) ? Wk : (z == 2) ? Wv : Wo;
  u16* out = WT + (size_t)z * 1048576;
  const int R0 = blockIdx.y * 64, C0 = blockIdx.x * 64;
  const int t = threadIdx.x;
#pragma unroll
  for (int it = 0; it < 16; ++it) {
    int j = it * 256 + t;
    int r = j >> 6, c = j & 63;
    tile[r * 68 + c] = f2bf(W[(size_t)(R0 + r) * 1024 + C0 + c]);
  }
  __syncthreads();
#pragma unroll
  for (int it = 0; it < 16; ++it) {
    int j = it * 256 + t;
    int c = j >> 6, r = j & 63;
    out[(size_t)(C0 + c) * 1024 + R0 + r] = tile[r * 68 + c];
  }
}

// -------------------------------------------------- fused QKV projection GEMM
// BK=64, 16 k-iters, uniform C^T orientation (regs = n = d-dim) for ALL z.
// Epilogue bounces acc through LDS so every global store is a 256B-contiguous
// run (full-line coverage). z=0: Q natural [b,s,1024] pre-scaled by CSC;
// z=1: K natural [b,s,1024]; z=2: V^T [b,h,d,s].
// XCD swizzle: 1-D grid of 256 tiles, m_tile = T&31 -> same-A-stripe blocks
// share an XCD (xcd = T%8 = m%8); per-XCD: 4 A-stripes + full B = 3MB < 4MB L2.
__global__ __launch_bounds__(256, 3)
void qkv_gemm(const u16* __restrict__ XB, const u16* __restrict__ WT,
              const float* __restrict__ bq, const float* __restrict__ bk,
              const float* __restrict__ bv,
              u16* __restrict__ QN, u16* __restrict__ KN, u16* __restrict__ VT) {
  __shared__ u16 smem[16896];          // lA(8192) + lB(8192); reused as 128x132 bounce
  u16* lA = smem;
  u16* lB = smem + 8192;
  const int z = blockIdx.y;
  const u16* A  = XB + (size_t)z * 4194304;
  const u16* Bt = WT + (size_t)z * 1048576;
  const float* bias = (z == 0) ? bq : (z == 1) ? bk : bv;
  const int T = blockIdx.x;
  const int m0 = (T & 31) * 128, n0 = (T >> 5) * 128;
  const int t = threadIdx.x, lane = t & 63, w = t >> 6;
  const int quad = lane >> 4, l16 = lane & 15;
  const int wm = (w & 1) * 64, wn = (w >> 1) * 64;

  f32x4 acc[4][4] = {};
  for (int kt = 0; kt < 16; ++kt) {
    const int k0 = kt * 64;
#pragma unroll
    for (int it = 0; it < 4; ++it) {
      int i = it * 256 + t;
      int r = i >> 3, cc = i & 7, c = cc ^ (r & 7);
      async16(A + (size_t)(m0 + r) * 1024 + k0 + c * 8, &lA[i * 8]);
      async16(Bt + (size_t)(n0 + r) * 1024 + k0 + c * 8, &lB[i * 8]);
    }
    __syncthreads();
#pragma unroll
    for (int ks = 0; ks < 2; ++ks) {
      bf16x8 af[4], bfr[4];
#pragma unroll
      for (int rt = 0; rt < 4; ++rt) {
        int row = wm + rt * 16 + l16;
        af[rt] = *(const bf16x8*)&lA[row * 64 + ((ks * 4 + quad) ^ (row & 7)) * 8];
      }
#pragma unroll
      for (int ct = 0; ct < 4; ++ct) {
        int row = wn + ct * 16 + l16;
        bfr[ct] = *(const bf16x8*)&lB[row * 64 + ((ks * 4 + quad) ^ (row & 7)) * 8];
      }
#pragma unroll
      for (int rt = 0; rt < 4; ++rt)
#pragma unroll
        for (int ct = 0; ct < 4; ++ct)
          acc[rt][ct] = mfma16(bfr[ct], af[rt], acc[rt][ct]);  // C^T: regs = d
    }
    __syncthreads();
  }

  // ---- epilogue via LDS bounce (all waves past final barrier; smem reusable)
  if (z < 2) {
    const float scl = (z == 0) ? CSC : 1.0f;
    // acc -> smem[s][132 + d]  (s-local = wm+rt*16+l16, d-local = wn+ct*16+quad*4)
#pragma unroll
    for (int rt = 0; rt < 4; ++rt) {
      int sl = wm + rt * 16 + l16;
#pragma unroll
      for (int ct = 0; ct < 4; ++ct) {
        int nb = wn + ct * 16 + quad * 4;
        float4 b4 = *(const float4*)&bias[n0 + nb];
        ushort4 pk;
        pk.x = f2bf((acc[rt][ct][0] + b4.x) * scl);
        pk.y = f2bf((acc[rt][ct][1] + b4.y) * scl);
        pk.z = f2bf((acc[rt][ct][2] + b4.z) * scl);
        pk.w = f2bf((acc[rt][ct][3] + b4.w) * scl);
        *(ushort4*)&smem[sl * 132 + nb] = pk;
      }
    }
    __syncthreads();
    // coalesced store: natural [4096][1024]; 256B-contiguous per 16 lanes
    u16* out = (z == 0) ? QN : KN;
#pragma unroll
    for (int p = 0; p < 8; ++p) {
      int idx = p * 256 + t;
      int row = idx >> 4, chunk = idx & 15;
      *(bf16x8*)&out[(size_t)(m0 + row) * 1024 + n0 + chunk * 8] =
          *(const bf16x8*)&smem[row * 132 + chunk * 8];
    }
  } else {
    // acc -> smem[d][132 + s] (transpose via scalar LDS writes)
#pragma unroll
    for (int rt = 0; rt < 4; ++rt) {
      int sl = wm + rt * 16 + l16;
#pragma unroll
      for (int ct = 0; ct < 4; ++ct) {
        int nb = wn + ct * 16 + quad * 4;
        float4 b4 = *(const float4*)&bias[n0 + nb];
        smem[(nb + 0) * 132 + sl] = f2bf(acc[rt][ct][0] + b4.x);
        smem[(nb + 1) * 132 + sl] = f2bf(acc[rt][ct][1] + b4.y);
        smem[(nb + 2) * 132 + sl] = f2bf(acc[rt][ct][2] + b4.z);
        smem[(nb + 3) * 132 + sl] = f2bf(acc[rt][ct][3] + b4.w);
      }
    }
    __syncthreads();
    // coalesced store: VT[b,h,d,s]; 256B-contiguous per 16 lanes
    const int bb = m0 >> 11, sb = m0 & 2047;
#pragma unroll
    for (int p = 0; p < 8; ++p) {
      int idx = p * 256 + t;
      int dl = idx >> 4, chunk = idx & 15;
      int ncol = n0 + dl, hh = ncol >> 6, dd = ncol & 63;
      *(bf16x8*)&VT[((size_t)((bb * 16 + hh) * 64 + dd)) * 2048 + sb + chunk * 8] =
          *(const bf16x8*)&smem[dl * 132 + chunk * 8];
    }
  }
}

// -------------------------------------------------------- flash attention
// attn10 = attn9 (52.9us; MFMA 30% / VALU 41% / ~3x issue-vs-wallclock gap
// => stalled on the per-tile __syncthreads' implicit vmcnt(0), which drains
// the just-issued next-tile global_load_lds every tile) with the T3/T4
// counted-vmcnt pipeline:
//   4-deep K/V ring buffer. At iter kt: issue tile kt+2's loads (2 per
//   thread); s_waitcnt vmcnt(4) — lets kt+1/kt+2's 4 loads stay in flight,
//   guarantees kt's landed; raw s_barrier + sched_barrier(0); compute
//   buf[kt&3]. ONE barrier/tile, never a full drain in steady state.
//   Safety (D=4): a wave at iter-kt top passed barrier(kt-1) [collective]
//   => all waves finished compute(kt-2); the issue overwrites buf[(kt+2)&3]
//   = buf[(kt-2)&3] — provably quiescent. D=3 would race.
//   Tail: vmcnt(2) @ kt=30, vmcnt(0) @ kt=31. No other VMEM in the loop,
//   so counts are exact. LDS 64 KB -> still 2 blocks/CU.
// Keeps: sigma-permuted K staging (P stays in registers), ones-MFMA row-sum,
// 512 thr / 8 waves x 16 q, grid (16,16,2).
__global__ __launch_bounds__(512, 4)
void attn10(const u16* __restrict__ QN, const u16* __restrict__ KN,
            const u16* __restrict__ VT, u16* __restrict__ AO) {
  __shared__ u16 lK[4][64 * 64];
  __shared__ u16 lV[4][64 * 64];
  const int qt0 = blockIdx.x, h = blockIdx.y, b = blockIdx.z;
  const int t = threadIdx.x, lane = t & 63, w = t >> 6;
  const int quad = lane >> 4, l16 = lane & 15;
  const u16* Qg = QN + ((size_t)(b * 2048 + qt0 * 128)) * 1024 + h * 64;
  const u16* Kg = KN + ((size_t)b * 2048) * 1024 + h * 64;
  const u16* Vg = VT + ((size_t)((b * 16 + h) * 64)) * 2048;

  // sigma(r): bit4<-bit3, bit3<-bit2, bit2<-bit4 (bits 5,1,0 fixed)
  const int sr_r = t >> 3;  // LDS row this thread stages
  const int sg_r = (sr_r & 0x23) | ((sr_r & 8) << 1) | ((sr_r & 4) << 1) |
                   ((sr_r & 16) >> 2);
  const int sc_c = (t & 7) ^ (sr_r & 7);  // pre-swizzled source chunk

  // Q fragments straight from global (pre-scaled by CSC in qkv_gemm)
  bf16x8 qf[2];
#pragma unroll
  for (int ks = 0; ks < 2; ++ks)
    qf[ks] = *(const bf16x8*)(Qg + (size_t)(w * 16 + l16) * 1024 + ks * 32 + quad * 8);

  // bf16 1.0 x8 (A-operand of the ones-MFMA row-sum)
  const bf16x8 ones = {0x3F80, 0x3F80, 0x3F80, 0x3F80,
                       0x3F80, 0x3F80, 0x3F80, 0x3F80};

  // prologue: stage tiles 0 and 1 (K sigma-permuted rows, V linear)
  async16(Kg + (size_t)sg_r * 1024 + sc_c * 8, &lK[0][t * 8]);
  async16(Vg + (size_t)sr_r * 2048 + sc_c * 8, &lV[0][t * 8]);
  async16(Kg + (size_t)(64 + sg_r) * 1024 + sc_c * 8, &lK[1][t * 8]);
  async16(Vg + (size_t)sr_r * 2048 + 64 + sc_c * 8, &lV[1][t * 8]);

  f32x4 o[4] = {};
  f32x4 ls = {};   // ls[0] accumulates sum_sk P[sk][q=l16] via ones-MFMA

  for (int kt = 0; kt < 32; ++kt) {
    if (kt + 2 < 32) {
      const int kb = (kt + 2) * 64;
      const int nb2 = (kt + 2) & 3;
      async16(Kg + (size_t)(kb + sg_r) * 1024 + sc_c * 8, &lK[nb2][t * 8]);
      async16(Vg + (size_t)sr_r * 2048 + kb + sc_c * 8, &lV[nb2][t * 8]);
    }
    // counted wait: tile kt's 2 loads landed; kt+1/kt+2's may stay in flight
    if (kt < 30)       asm volatile("s_waitcnt vmcnt(4)" ::: "memory");
    else if (kt == 30) asm volatile("s_waitcnt vmcnt(2)" ::: "memory");
    else               asm volatile("s_waitcnt vmcnt(0)" ::: "memory");
    __builtin_amdgcn_s_barrier();
    __builtin_amdgcn_sched_barrier(0);

    const int cur = kt & 3;

    // ---- QK^T -> S^T (sigma-permuted rows): lane holds sk'=16st+4quad+r
    f32x4 sc[4];
    __builtin_amdgcn_s_setprio(1);
#pragma unroll
    for (int st = 0; st < 4; ++st) {
      int row = st * 16 + l16;
      bf16x8 kf0 = *(const bf16x8*)&lK[cur][row * 64 + ((quad) ^ (row & 7)) * 8];
      bf16x8 kf1 = *(const bf16x8*)&lK[cur][row * 64 + ((4 + quad) ^ (row & 7)) * 8];
      f32x4 z = {};
      sc[st] = mfma16(kf0, qf[0], z);
      sc[st] = mfma16(kf1, qf[1], sc[st]);
    }
    __builtin_amdgcn_s_setprio(0);

    // ---- p = exp2(s); pack directly into PV fragments (no LDS, no VALU sum)
    union { uint32_t u[4]; bf16x8 v; } pf0c, pf1c;
#pragma unroll
    for (int st = 0; st < 2; ++st) {
      pf0c.u[st * 2 + 0] = pk2bf(EXP2F(sc[st][0]), EXP2F(sc[st][1]));
      pf0c.u[st * 2 + 1] = pk2bf(EXP2F(sc[st][2]), EXP2F(sc[st][3]));
      pf1c.u[st * 2 + 0] = pk2bf(EXP2F(sc[2 + st][0]), EXP2F(sc[2 + st][1]));
      pf1c.u[st * 2 + 1] = pk2bf(EXP2F(sc[2 + st][2]), EXP2F(sc[2 + st][3]));
    }

    // ---- PV: O^T += V^T(64d x 64sk) * P(16q x 64sk), P from registers.
    //      Row-sum on the MFMA pipe: ls += ones^T * P.
    __builtin_amdgcn_s_setprio(1);
    ls = mfma16(ones, pf0c.v, ls);
    ls = mfma16(ones, pf1c.v, ls);
#pragma unroll
    for (int dt = 0; dt < 4; ++dt) {
      int row = dt * 16 + l16;
      bf16x8 vf0 = *(const bf16x8*)&lV[cur][row * 64 + ((quad) ^ (row & 7)) * 8];
      bf16x8 vf1 = *(const bf16x8*)&lV[cur][row * 64 + ((4 + quad) ^ (row & 7)) * 8];
      o[dt] = mfma16(vf0, pf0c.v, o[dt]);
      o[dt] = mfma16(vf1, pf1c.v, o[dt]);
    }
    __builtin_amdgcn_s_setprio(0);
  }

  // ---- epilogue: O^T/l -> AO [b][s][h*64+d] bf16 (4 consecutive d per lane)
  // ls[0] holds the complete row sum for q=l16 in EVERY lane.
  float inv = 1.0f / ls[0];
  int qglob = qt0 * 128 + w * 16 + l16;
  size_t base = ((size_t)(b * 2048 + qglob)) * 1024 + h * 64;
#pragma unroll
  for (int dt = 0; dt < 4; ++dt) {
    ushort4 pk;
    pk.x = f2bf(o[dt][0] * inv);
    pk.y = f2bf(o[dt][1] * inv);
    pk.z = f2bf(o[dt][2] * inv);
    pk.w = f2bf(o[dt][3] * inv);
    *(ushort4*)&AO[base + dt * 16 + quad * 4] = pk;
  }
}

// ------------------------------------------------------- output projection
// 128m x 64n tiles, BK=64, 512 blocks, XCD swizzle (m_tile = T&31).
// Normal orientation; scalar f32 stores = 64B runs (R3-style, known-good).
__global__ __launch_bounds__(256, 2)
void oproj_gemm(const u16* __restrict__ AO, const u16* __restrict__ Bt,
                const float* __restrict__ bias, float* __restrict__ out) {
  __shared__ u16 lA[128 * 64];
  __shared__ u16 lB[64 * 64];
  const int T = blockIdx.x;
  const int m0 = (T & 31) * 128, n0 = (T >> 5) * 64;
  const int t = threadIdx.x, lane = t & 63, w = t >> 6;
  const int quad = lane >> 4, l16 = lane & 15;
  const int wm = (w & 1) * 64, wn = (w >> 1) * 32;

  f32x4 acc[4][2] = {};
  for (int kt = 0; kt < 16; ++kt) {
    const int k0 = kt * 64;
#pragma unroll
    for (int it = 0; it < 4; ++it) {
      int i = it * 256 + t;
      int r = i >> 3, cc = i & 7, c = cc ^ (r & 7);
      async16(AO + (size_t)(m0 + r) * 1024 + k0 + c * 8, &lA[i * 8]);
    }
#pragma unroll
    for (int it = 0; it < 2; ++it) {
      int i = it * 256 + t;
      int r = i >> 3, cc = i & 7, c = cc ^ (r & 7);
      async16(Bt + (size_t)(n0 + r) * 1024 + k0 + c * 8, &lB[i * 8]);
    }
    __syncthreads();
#pragma unroll
    for (int ks = 0; ks < 2; ++ks) {
      bf16x8 af[4], bfr[2];
#pragma unroll
      for (int rt = 0; rt < 4; ++rt) {
        int row = wm + rt * 16 + l16;
        af[rt] = *(const bf16x8*)&lA[row * 64 + ((ks * 4 + quad) ^ (row & 7)) * 8];
      }
#pragma unroll
      for (int ct = 0; ct < 2; ++ct) {
        int row = wn + ct * 16 + l16;
        bfr[ct] = *(const bf16x8*)&lB[row * 64 + ((ks * 4 + quad) ^ (row & 7)) * 8];
      }
#pragma unroll
      for (int rt = 0; rt < 4; ++rt)
#pragma unroll
        for (int ct = 0; ct < 2; ++ct)
          acc[rt][ct] = mfma16(af[rt], bfr[ct], acc[rt][ct]);
    }
    __syncthreads();
  }

#pragma unroll
  for (int ct = 0; ct < 2; ++ct) {
    int ncol = n0 + wn + ct * 16 + l16;
    float bvv = bias[ncol];
#pragma unroll
    for (int rt = 0; rt < 4; ++rt)
#pragma unroll
      for (int r = 0; r < 4; ++r) {
        int m = m0 + wm + rt * 16 + quad * 4 + r;
        out[(size_t)m * 1024 + ncol] = acc[rt][ct][r] + bvv;
      }
  }
}

// ------------------------------------------------------------------ launch
extern "C" void kernel_launch(void* const* d_in, const int* in_sizes, int n_in,
                              void* d_out, int out_size, void* d_ws, size_t ws_size,
                              hipStream_t stream) {
  const float* query = (const float*)d_in[0];
  const float* key   = (const float*)d_in[1];
  const float* value = (const float*)d_in[2];
  const float* Wq = (const float*)d_in[3];
  const float* bq = (const float*)d_in[4];
  const float* Wk = (const float*)d_in[5];
  const float* bk = (const float*)d_in[6];
  const float* Wv = (const float*)d_in[7];
  const float* bv = (const float*)d_in[8];
  const float* Wo = (const float*)d_in[9];
  const float* bo = (const float*)d_in[10];
  float* out = (float*)d_out;

  // workspace layout (u16 elements): total 28M u16 = 56 MB
  u16* WT = (u16*)d_ws;              // 4 x 1M  (Wq_t, Wk_t, Wv_t, Wo_t)
  u16* QN = WT + 4 * 1048576;        // 4M  natural [b,s,1024] (pre-scaled by CSC)
  u16* KN = QN + 4194304;            // 4M  natural [b,s,1024]
  u16* VT = KN + 4194304;            // 4M  [b,h,d,s]
  u16* XB = VT + 4194304;            // 3 x 4M bf16 copies of q,k,v
  u16* AO = XB;                      // attn out aliases XB (dead by then)

  convx<<<dim3(4096, 3), 256, 0, stream>>>(query, key, value, XB);
  transw<<<dim3(16, 16, 4), 256, 0, stream>>>(Wq, Wk, Wv, Wo, WT);
  qkv_gemm<<<dim3(256, 3), 256, 0, stream>>>(XB, WT, bq, bk, bv, QN, KN, VT);
  attn10<<<dim3(16, 16, 2), 512, 0, stream>>>(QN, KN, VT, AO);
  oproj_gemm<<<dim3(512), 256, 0, stream>>>(AO, WT + 3 * 1048576, bo, out);
}